// Round 6
// baseline (338.755 us; speedup 1.0000x reference)
//
#include <hip/hip_runtime.h>
#include <hip/hip_bf16.h>

#define NUM_USER 100000
#define K_NEIGH 32
#define DIM 64

typedef float floatx2 __attribute__((ext_vector_type(2)));
typedef float floatx4 __attribute__((ext_vector_type(4)));
typedef unsigned int uintx2 __attribute__((ext_vector_type(2)));

// Kernel 1: compress fp32 features -> packed bf16x2 table (RNE).
__global__ __launch_bounds__(256) void convert_bf16_kernel(
    const floatx2* __restrict__ feat2,   // 3.2M float2
    unsigned int*  __restrict__ table) { // 3.2M packed bf16x2
  int i = blockIdx.x * blockDim.x + threadIdx.x;
  if (i >= NUM_USER * DIM / 2) return;
  floatx2 f = feat2[i];
  unsigned int ux = __float_as_uint(f.x);
  unsigned int uy = __float_as_uint(f.y);
  unsigned int bx = (ux + 0x7fffu + ((ux >> 16) & 1u)) >> 16;
  unsigned int by = (uy + 0x7fffu + ((uy >> 16) & 1u)) >> 16;
  table[i] = bx | (by << 16);
}

// Kernel 2: per-user sort of (idx, weight) pairs by idx, ascending.
// One user per thread; 32-element bitonic network fully in registers.
// Sorted order makes the gather sweep the table monotonically -> all CUs
// share a narrow L2-resident index band at any instant.
__global__ __launch_bounds__(256) void sort_pairs_kernel(
    const int*   __restrict__ graph,
    const float* __restrict__ matrix,
    uintx2*      __restrict__ pairs) {   // [NUM_USER][32] {idx, w-bits}
  int u = blockIdx.x * blockDim.x + threadIdx.x;
  if (u >= NUM_USER) return;
  const int*   g = graph  + u * K_NEIGH;
  const float* w = matrix + u * K_NEIGH;
  int   idx[K_NEIGH];
  float wv[K_NEIGH];
#pragma unroll
  for (int k = 0; k < K_NEIGH; ++k) { idx[k] = g[k]; wv[k] = w[k]; }
  // bitonic sort, key = idx
#pragma unroll
  for (int k = 2; k <= K_NEIGH; k <<= 1) {
#pragma unroll
    for (int j = k >> 1; j > 0; j >>= 1) {
#pragma unroll
      for (int i = 0; i < K_NEIGH; ++i) {
        int l = i ^ j;
        if (l > i) {
          bool up = ((i & k) == 0);
          bool sw = up ? (idx[i] > idx[l]) : (idx[i] < idx[l]);
          int   ti = sw ? idx[l] : idx[i];
          int   tl = sw ? idx[i] : idx[l];
          float si = sw ? wv[l]  : wv[i];
          float sl = sw ? wv[i]  : wv[l];
          idx[i] = ti; idx[l] = tl; wv[i] = si; wv[l] = sl;
        }
      }
    }
  }
#pragma unroll
  for (int k = 0; k < K_NEIGH; ++k) {
    uintx2 p; p.x = (unsigned int)idx[k]; p.y = __float_as_uint(wv[k]);
    pairs[u * K_NEIGH + k] = p;
  }
}

// Kernel 3: gather+weighted-sum from bf16 table using sorted pairs.
// 16 lanes per user; each lane owns dims {4*d4 .. 4*d4+3} (8B = 4 bf16).
__global__ __launch_bounds__(256) void user_graph_gather_bf16_kernel(
    const uintx2* __restrict__ table2,  // [NUM_USER][16] bf16x4 chunks
    const uintx2* __restrict__ pairs,   // [NUM_USER][32] sorted {idx, w}
    floatx4*      __restrict__ out4) {  // [NUM_USER][16] float4
  int t  = blockIdx.x * blockDim.x + threadIdx.x;
  int u  = t >> 4;
  int d4 = t & 15;
  if (u >= NUM_USER) return;

  const uintx2* pp = pairs + u * K_NEIGH;

  float a0 = 0.f, a1 = 0.f, a2 = 0.f, a3 = 0.f;
#pragma unroll
  for (int k = 0; k < K_NEIGH; ++k) {
    uintx2 p  = pp[k];                      // uniform per 16-lane group
    int    idx = (int)p.x;
    float  wk  = __uint_as_float(p.y);
    uintx2 f  = table2[idx * 16 + d4];      // 16 lanes x 8B = one 128B line
    a0 += wk * __uint_as_float(f.x << 16);
    a1 += wk * __uint_as_float(f.x & 0xffff0000u);
    a2 += wk * __uint_as_float(f.y << 16);
    a3 += wk * __uint_as_float(f.y & 0xffff0000u);
  }
  floatx4 r; r.x = a0; r.y = a1; r.z = a2; r.w = a3;
  out4[u * 16 + d4] = r;
}

// Fallback A (ws >= table only): round-5 gather without sort.
__global__ __launch_bounds__(256) void gather_bf16_nosort_kernel(
    const uintx2* __restrict__ table2,
    const int*    __restrict__ graph,
    const float*  __restrict__ matrix,
    floatx4*      __restrict__ out4) {
  int t  = blockIdx.x * blockDim.x + threadIdx.x;
  int u  = t >> 4;
  int d4 = t & 15;
  if (u >= NUM_USER) return;
  const int*   g = graph  + u * K_NEIGH;
  const float* w = matrix + u * K_NEIGH;
  float a0 = 0.f, a1 = 0.f, a2 = 0.f, a3 = 0.f;
#pragma unroll
  for (int k = 0; k < K_NEIGH; ++k) {
    int   idx = g[k];
    float wk  = w[k];
    uintx2 f  = table2[idx * 16 + d4];
    a0 += wk * __uint_as_float(f.x << 16);
    a1 += wk * __uint_as_float(f.x & 0xffff0000u);
    a2 += wk * __uint_as_float(f.y << 16);
    a3 += wk * __uint_as_float(f.y & 0xffff0000u);
  }
  floatx4 r; r.x = a0; r.y = a1; r.z = a2; r.w = a3;
  out4[u * 16 + d4] = r;
}

// Fallback B (tiny ws): round-1 fp32 gather.
__global__ __launch_bounds__(256) void user_graph_gather_f32_kernel(
    const float* __restrict__ features,
    const int*   __restrict__ graph,
    const float* __restrict__ matrix,
    float*       __restrict__ out) {
  int t = blockIdx.x * blockDim.x + threadIdx.x;
  int u = t >> 6;
  int d = t & 63;
  if (u >= NUM_USER) return;
  const int*   g = graph  + (size_t)u * K_NEIGH;
  const float* w = matrix + (size_t)u * K_NEIGH;
  float acc = 0.f;
#pragma unroll
  for (int k = 0; k < K_NEIGH; ++k)
    acc += w[k] * features[(size_t)g[k] * DIM + d];
  out[(size_t)u * DIM + d] = acc;
}

extern "C" void kernel_launch(void* const* d_in, const int* in_sizes, int n_in,
                              void* d_out, int out_size, void* d_ws, size_t ws_size,
                              hipStream_t stream) {
  const float* features = (const float*)d_in[0];
  const int*   graph    = (const int*)d_in[1];
  const float* matrix   = (const float*)d_in[2];

  const size_t table_bytes = (size_t)NUM_USER * DIM * 2;          // 12.8 MB
  const size_t pairs_bytes = (size_t)NUM_USER * K_NEIGH * 8;      // 25.6 MB

  if (ws_size >= table_bytes + pairs_bytes) {
    unsigned int* table = (unsigned int*)d_ws;
    uintx2*       pairs = (uintx2*)((char*)d_ws + table_bytes);

    const int n_pack = NUM_USER * DIM / 2;  // 3.2M
    convert_bf16_kernel<<<(n_pack + 255) / 256, 256, 0, stream>>>(
        (const floatx2*)features, table);
    sort_pairs_kernel<<<(NUM_USER + 255) / 256, 256, 0, stream>>>(
        graph, matrix, pairs);
    const int total = NUM_USER * 16;        // 1.6M threads
    user_graph_gather_bf16_kernel<<<(total + 255) / 256, 256, 0, stream>>>(
        (const uintx2*)table, (const uintx2*)pairs, (floatx4*)d_out);
  } else if (ws_size >= table_bytes) {
    unsigned int* table = (unsigned int*)d_ws;
    const int n_pack = NUM_USER * DIM / 2;
    convert_bf16_kernel<<<(n_pack + 255) / 256, 256, 0, stream>>>(
        (const floatx2*)features, table);
    const int total = NUM_USER * 16;
    gather_bf16_nosort_kernel<<<(total + 255) / 256, 256, 0, stream>>>(
        (const uintx2*)table, graph, matrix, (floatx4*)d_out);
  } else {
    const int total = NUM_USER * DIM;
    user_graph_gather_f32_kernel<<<(total + 255) / 256, 256, 0, stream>>>(
        features, graph, matrix, (float*)d_out);
  }
}

// Round 7
// 157.706 us; speedup vs baseline: 2.1480x; 2.1480x over previous
//
#include <hip/hip_runtime.h>
#include <hip/hip_bf16.h>

#define NUM_USER 100000
#define K_NEIGH 32
#define DIM 64

typedef float floatx2 __attribute__((ext_vector_type(2)));
typedef float floatx4 __attribute__((ext_vector_type(4)));
typedef unsigned int uintx2 __attribute__((ext_vector_type(2)));

// Kernel 1: compress fp32 features -> packed bf16x2 table (RNE).
__global__ __launch_bounds__(256) void convert_bf16_kernel(
    const floatx2* __restrict__ feat2,   // 3.2M float2
    unsigned int*  __restrict__ table) { // 3.2M packed bf16x2
  int i = blockIdx.x * blockDim.x + threadIdx.x;
  if (i >= NUM_USER * DIM / 2) return;
  floatx2 f = feat2[i];
  unsigned int ux = __float_as_uint(f.x);
  unsigned int uy = __float_as_uint(f.y);
  unsigned int bx = (ux + 0x7fffu + ((ux >> 16) & 1u)) >> 16;
  unsigned int by = (uy + 0x7fffu + ((uy >> 16) & 1u)) >> 16;
  table[i] = bx | (by << 16);
}

// Kernel 2: wave-level bitonic sort of each user's 32 (idx, weight) pairs.
// 32 lanes per user, one pair per lane, shfl_xor compare-exchange network —
// no per-thread arrays, no spill (round-6 register-array version spilled
// to scratch and ran 210us).
__global__ __launch_bounds__(256) void sort_pairs_wave_kernel(
    const int*   __restrict__ graph,
    const float* __restrict__ matrix,
    uintx2*      __restrict__ pairs) {   // [NUM_USER][32] {idx, w-bits}
  int t = blockIdx.x * blockDim.x + threadIdx.x;
  int u = t >> 5;          // 32 lanes per user, 2 users per wave
  int k = t & 31;
  if (u >= NUM_USER) return;

  int   idx = graph[u * K_NEIGH + k];    // coalesced
  float w   = matrix[u * K_NEIGH + k];

#pragma unroll
  for (int sz = 2; sz <= 32; sz <<= 1) {
#pragma unroll
    for (int j = sz >> 1; j > 0; j >>= 1) {
      int   oi = __shfl_xor(idx, j);     // j<32: stays within the 32-lane half
      float ow = __shfl_xor(w, j);
      bool up         = ((k & sz) == 0); // sz==32: always ascending
      bool lower      = ((k & j) == 0);
      bool keep_small = (lower == up);
      bool take       = keep_small ? (oi < idx) : (oi > idx);
      idx = take ? oi : idx;
      w   = take ? ow : w;
    }
  }
  uintx2 p; p.x = (unsigned int)idx; p.y = __float_as_uint(w);
  pairs[u * K_NEIGH + k] = p;            // 8B/lane coalesced
}

// Kernel 3: gather+weighted-sum from bf16 table using sorted pairs.
// 16 lanes per user; each lane owns dims {4*d4 .. 4*d4+3} (8B = 4 bf16).
__global__ __launch_bounds__(256) void user_graph_gather_bf16_kernel(
    const uintx2* __restrict__ table2,  // [NUM_USER][16] bf16x4 chunks
    const uintx2* __restrict__ pairs,   // [NUM_USER][32] sorted {idx, w}
    floatx4*      __restrict__ out4) {  // [NUM_USER][16] float4
  int t  = blockIdx.x * blockDim.x + threadIdx.x;
  int u  = t >> 4;
  int d4 = t & 15;
  if (u >= NUM_USER) return;

  const uintx2* pp = pairs + u * K_NEIGH;

  float a0 = 0.f, a1 = 0.f, a2 = 0.f, a3 = 0.f;
#pragma unroll
  for (int k = 0; k < K_NEIGH; ++k) {
    uintx2 p  = pp[k];                      // uniform per 16-lane group
    int    idx = (int)p.x;
    float  wk  = __uint_as_float(p.y);
    uintx2 f  = table2[idx * 16 + d4];      // 16 lanes x 8B = one 128B line
    a0 += wk * __uint_as_float(f.x << 16);
    a1 += wk * __uint_as_float(f.x & 0xffff0000u);
    a2 += wk * __uint_as_float(f.y << 16);
    a3 += wk * __uint_as_float(f.y & 0xffff0000u);
  }
  floatx4 r; r.x = a0; r.y = a1; r.z = a2; r.w = a3;
  out4[u * 16 + d4] = r;
}

// Fallback A (ws >= table only): round-5 gather without sort.
__global__ __launch_bounds__(256) void gather_bf16_nosort_kernel(
    const uintx2* __restrict__ table2,
    const int*    __restrict__ graph,
    const float*  __restrict__ matrix,
    floatx4*      __restrict__ out4) {
  int t  = blockIdx.x * blockDim.x + threadIdx.x;
  int u  = t >> 4;
  int d4 = t & 15;
  if (u >= NUM_USER) return;
  const int*   g = graph  + u * K_NEIGH;
  const float* w = matrix + u * K_NEIGH;
  float a0 = 0.f, a1 = 0.f, a2 = 0.f, a3 = 0.f;
#pragma unroll
  for (int k = 0; k < K_NEIGH; ++k) {
    int   idx = g[k];
    float wk  = w[k];
    uintx2 f  = table2[idx * 16 + d4];
    a0 += wk * __uint_as_float(f.x << 16);
    a1 += wk * __uint_as_float(f.x & 0xffff0000u);
    a2 += wk * __uint_as_float(f.y << 16);
    a3 += wk * __uint_as_float(f.y & 0xffff0000u);
  }
  floatx4 r; r.x = a0; r.y = a1; r.z = a2; r.w = a3;
  out4[u * 16 + d4] = r;
}

// Fallback B (tiny ws): round-1 fp32 gather.
__global__ __launch_bounds__(256) void user_graph_gather_f32_kernel(
    const float* __restrict__ features,
    const int*   __restrict__ graph,
    const float* __restrict__ matrix,
    float*       __restrict__ out) {
  int t = blockIdx.x * blockDim.x + threadIdx.x;
  int u = t >> 6;
  int d = t & 63;
  if (u >= NUM_USER) return;
  const int*   g = graph  + (size_t)u * K_NEIGH;
  const float* w = matrix + (size_t)u * K_NEIGH;
  float acc = 0.f;
#pragma unroll
  for (int k = 0; k < K_NEIGH; ++k)
    acc += w[k] * features[(size_t)g[k] * DIM + d];
  out[(size_t)u * DIM + d] = acc;
}

extern "C" void kernel_launch(void* const* d_in, const int* in_sizes, int n_in,
                              void* d_out, int out_size, void* d_ws, size_t ws_size,
                              hipStream_t stream) {
  const float* features = (const float*)d_in[0];
  const int*   graph    = (const int*)d_in[1];
  const float* matrix   = (const float*)d_in[2];

  const size_t table_bytes = (size_t)NUM_USER * DIM * 2;          // 12.8 MB
  const size_t pairs_bytes = (size_t)NUM_USER * K_NEIGH * 8;      // 25.6 MB

  if (ws_size >= table_bytes + pairs_bytes) {
    unsigned int* table = (unsigned int*)d_ws;
    uintx2*       pairs = (uintx2*)((char*)d_ws + table_bytes);

    const int n_pack = NUM_USER * DIM / 2;  // 3.2M
    convert_bf16_kernel<<<(n_pack + 255) / 256, 256, 0, stream>>>(
        (const floatx2*)features, table);
    const int n_sort = NUM_USER * 32;       // 3.2M threads
    sort_pairs_wave_kernel<<<(n_sort + 255) / 256, 256, 0, stream>>>(
        graph, matrix, pairs);
    const int total = NUM_USER * 16;        // 1.6M threads
    user_graph_gather_bf16_kernel<<<(total + 255) / 256, 256, 0, stream>>>(
        (const uintx2*)table, (const uintx2*)pairs, (floatx4*)d_out);
  } else if (ws_size >= table_bytes) {
    unsigned int* table = (unsigned int*)d_ws;
    const int n_pack = NUM_USER * DIM / 2;
    convert_bf16_kernel<<<(n_pack + 255) / 256, 256, 0, stream>>>(
        (const floatx2*)features, table);
    const int total = NUM_USER * 16;
    gather_bf16_nosort_kernel<<<(total + 255) / 256, 256, 0, stream>>>(
        (const uintx2*)table, graph, matrix, (floatx4*)d_out);
  } else {
    const int total = NUM_USER * DIM;
    user_graph_gather_f32_kernel<<<(total + 255) / 256, 256, 0, stream>>>(
        features, graph, matrix, (float*)d_out);
  }
}

// Round 8
// 139.729 us; speedup vs baseline: 2.4244x; 1.1287x over previous
//
#include <hip/hip_runtime.h>
#include <hip/hip_bf16.h>

#define NUM_USER 100000
#define K_NEIGH 32
#define DIM 64

typedef float floatx2 __attribute__((ext_vector_type(2)));
typedef float floatx4 __attribute__((ext_vector_type(4)));
typedef unsigned int uintx2 __attribute__((ext_vector_type(2)));

// Kernel 1: compress fp32 features -> packed bf16x2 table (RNE).
__global__ __launch_bounds__(256) void convert_bf16_kernel(
    const floatx2* __restrict__ feat2,   // 3.2M float2
    unsigned int*  __restrict__ table) { // 3.2M packed bf16x2
  int i = blockIdx.x * blockDim.x + threadIdx.x;
  if (i >= NUM_USER * DIM / 2) return;
  floatx2 f = feat2[i];
  unsigned int ux = __float_as_uint(f.x);
  unsigned int uy = __float_as_uint(f.y);
  unsigned int bx = (ux + 0x7fffu + ((ux >> 16) & 1u)) >> 16;
  unsigned int by = (uy + 0x7fffu + ((uy >> 16) & 1u)) >> 16;
  table[i] = bx | (by << 16);
}

// Kernel 2: gather+weighted-sum with forced memory-level parallelism.
// 16 lanes per user (4 users/wave); lane owns dims {4*d4..4*d4+3}.
// K-loop batched by 8: load 8 (idx,w) pairs, issue 8 independent table
// loads into live temporaries, then consume. Round-5/7 versions compiled
// to 32-36 VGPRs => serialized loads => latency-bound at ~3.2 TB/s.
__global__ __launch_bounds__(256) void gather_bf16_mlp_kernel(
    const uintx2* __restrict__ table2,   // [NUM_USER][16] bf16x4 chunks
    const int*    __restrict__ graph,    // [NUM_USER][32]
    const float*  __restrict__ matrix,   // [NUM_USER][32]
    floatx4*      __restrict__ out4) {   // [NUM_USER][16] float4
  int t  = blockIdx.x * blockDim.x + threadIdx.x;
  int u  = t >> 4;
  int d4 = t & 15;
  if (u >= NUM_USER) return;

  const int*   g = graph  + u * K_NEIGH;
  const float* w = matrix + u * K_NEIGH;

  float a0 = 0.f, a1 = 0.f, a2 = 0.f, a3 = 0.f;

#pragma unroll
  for (int kb = 0; kb < K_NEIGH; kb += 8) {
    int   idx[8];
    float wk[8];
#pragma unroll
    for (int j = 0; j < 8; ++j) {
      idx[j] = g[kb + j];                // uniform per 16-lane group
      wk[j]  = w[kb + j];
    }
    uintx2 f[8];                          // 8 concurrent 8B gathers in flight
#pragma unroll
    for (int j = 0; j < 8; ++j)
      f[j] = table2[idx[j] * 16 + d4];
#pragma unroll
    for (int j = 0; j < 8; ++j) {
      a0 += wk[j] * __uint_as_float(f[j].x << 16);
      a1 += wk[j] * __uint_as_float(f[j].x & 0xffff0000u);
      a2 += wk[j] * __uint_as_float(f[j].y << 16);
      a3 += wk[j] * __uint_as_float(f[j].y & 0xffff0000u);
    }
  }
  floatx4 r; r.x = a0; r.y = a1; r.z = a2; r.w = a3;
  out4[u * 16 + d4] = r;                 // 16B/lane coalesced store
}

// Fallback (tiny ws): round-1 fp32 gather, known-good.
__global__ __launch_bounds__(256) void user_graph_gather_f32_kernel(
    const float* __restrict__ features,
    const int*   __restrict__ graph,
    const float* __restrict__ matrix,
    float*       __restrict__ out) {
  int t = blockIdx.x * blockDim.x + threadIdx.x;
  int u = t >> 6;
  int d = t & 63;
  if (u >= NUM_USER) return;
  const int*   g = graph  + (size_t)u * K_NEIGH;
  const float* w = matrix + (size_t)u * K_NEIGH;
  float acc = 0.f;
#pragma unroll
  for (int k = 0; k < K_NEIGH; ++k)
    acc += w[k] * features[(size_t)g[k] * DIM + d];
  out[(size_t)u * DIM + d] = acc;
}

extern "C" void kernel_launch(void* const* d_in, const int* in_sizes, int n_in,
                              void* d_out, int out_size, void* d_ws, size_t ws_size,
                              hipStream_t stream) {
  const float* features = (const float*)d_in[0];
  const int*   graph    = (const int*)d_in[1];
  const float* matrix   = (const float*)d_in[2];

  const size_t table_bytes = (size_t)NUM_USER * DIM * 2;  // 12.8 MB bf16

  if (ws_size >= table_bytes) {
    unsigned int* table = (unsigned int*)d_ws;
    const int n_pack = NUM_USER * DIM / 2;  // 3.2M
    convert_bf16_kernel<<<(n_pack + 255) / 256, 256, 0, stream>>>(
        (const floatx2*)features, table);
    const int total = NUM_USER * 16;        // 1.6M threads
    gather_bf16_mlp_kernel<<<(total + 255) / 256, 256, 0, stream>>>(
        (const uintx2*)table, graph, matrix, (floatx4*)d_out);
  } else {
    const int total = NUM_USER * DIM;
    user_graph_gather_f32_kernel<<<(total + 255) / 256, 256, 0, stream>>>(
        features, graph, matrix, (float*)d_out);
  }
}